// Round 5
// baseline (344.021 us; speedup 1.0000x reference)
//
#include <hip/hip_runtime.h>
#include <hip/hip_bf16.h>
#include <math.h>

// B=2, C=128, H=W=64, heads=4, head_dim=32, kernel=7 (49 taps), depth=2.
// Inputs fp32, OUTPUT fp32 (reference returns float32). qkv intermediate bf16;
// y / attn intermediates fp32. ws use = 10 MB (y fp32 4MB + qkv bf16 6MB);
// attn (fp32 4MB) lives in d_out's lower half until the final LN write.
#define PIX 8192            // B*H*W
typedef __hip_bfloat16 bf16;

__device__ inline void store_val(bf16* p, float v)  { *p = __float2bfloat16(v); }
__device__ inline void store_val(float* p, float v) { *p = v; }

// ---------- input transpose: x (B,C,H,W) fp32 -> y (B,H,W,C) fp32 ----------
__global__ __launch_bounds__(256) void transpose_in(const float* __restrict__ x,
                                                    float* __restrict__ y) {
  __shared__ float tile[64][129];            // [j][c], +1 pad breaks bank conflicts
  int blk = blockIdx.x;                      // b*64 + i  (128 blocks)
  int tid = threadIdx.x;
  int b = blk >> 6, i = blk & 63;
  const float* xbase = x + (size_t)b * 128 * 4096 + (size_t)i * 64;
  for (int idx = tid; idx < 8192; idx += 256) {   // read coalesced along j
    int c = idx >> 6, j = idx & 63;
    tile[j][c] = xbase[(size_t)c * 4096 + j];
  }
  __syncthreads();
  float* yrow = y + (size_t)blk * 64 * 128;
  for (int idx = tid; idx < 8192; idx += 256) {   // write coalesced along c
    int j = idx >> 7, c = idx & 127;
    yrow[idx] = tile[j][c];
  }
}

// ---------- GEMM: C[M,N] = A[M,128] * W[N,128]^T + bias, M=8192 ----------
template <typename OutT>
__global__ __launch_bounds__(256) void gemm_nt(const float* __restrict__ A,
                                               const float* __restrict__ W,
                                               const float* __restrict__ bias,
                                               OutT* __restrict__ Cmat, int N) {
  __shared__ float As[64][65];
  __shared__ float Ws[64][65];
  int m0 = blockIdx.x * 64;
  int n0 = blockIdx.y * 64;
  int tid = threadIdx.x;
  int tx = tid & 15, ty = tid >> 4;
  float acc[4][4] = {{0.f}};
  for (int k0 = 0; k0 < 128; k0 += 64) {
    for (int idx = tid; idx < 4096; idx += 256) {
      int r = idx >> 6, c = idx & 63;
      As[r][c] = A[(size_t)(m0 + r) * 128 + k0 + c];
      Ws[r][c] = W[(size_t)(n0 + r) * 128 + k0 + c];
    }
    __syncthreads();
#pragma unroll 4
    for (int kk = 0; kk < 64; ++kk) {
      float a[4], w[4];
#pragma unroll
      for (int i = 0; i < 4; ++i) a[i] = As[ty * 4 + i][kk];
#pragma unroll
      for (int j = 0; j < 4; ++j) w[j] = Ws[tx * 4 + j][kk];
#pragma unroll
      for (int i = 0; i < 4; ++i)
#pragma unroll
        for (int j = 0; j < 4; ++j) acc[i][j] += a[i] * w[j];
    }
    __syncthreads();
  }
#pragma unroll
  for (int j = 0; j < 4; ++j) {
    float bv = bias[n0 + tx * 4 + j];
#pragma unroll
    for (int i = 0; i < 4; ++i)
      store_val(&Cmat[(size_t)(m0 + ty * 4 + i) * N + n0 + tx * 4 + j],
                acc[i][j] + bv);
  }
}

// ---------- neighborhood attention: 1 block/pixel, 1 wave/head ----------
// qkv per pixel row (384): [0:128]=q, [128:256]=k, [256:384]=v; head*32+dim.
__global__ __launch_bounds__(256) void na_attn(const bf16* __restrict__ qkv,
                                               const float* __restrict__ rpb,
                                               float* __restrict__ out) {
  int pix = blockIdx.x;
  int b = pix >> 12;
  int i = (pix >> 6) & 63;
  int j = pix & 63;
  int tid = threadIdx.x;
  int head = tid >> 6;          // wave id 0..3
  int lane = tid & 63;
  int dim = lane & 31;
  int half = lane >> 5;
  int si = min(max(i - 3, 0), 57);
  int sj = min(max(j - 3, 0), 57);
  __shared__ float sc[4][52];

  const float scale = 0.17677669529663687f;   // 32^-0.5
  float qv = __bfloat162float(qkv[(size_t)pix * 384 + head * 32 + dim]) * scale;

  for (int base = 0; base < 49; base += 2) {
    int n = base + half;
    float partial = 0.f;
    if (n < 49) {
      int p = n / 7, qq = n % 7;
      int np_ = ((b * 64 + si + p) * 64 + (sj + qq));
      partial = qv * __bfloat162float(qkv[(size_t)np_ * 384 + 128 + head * 32 + dim]);
    }
#pragma unroll
    for (int off = 16; off >= 1; off >>= 1) partial += __shfl_xor(partial, off);
    if (dim == 0 && n < 49) sc[head][n] = partial;
  }
  __syncthreads();

  float val = -INFINITY;
  int n = lane;
  if (n < 49) {
    int p = n / 7, qq = n % 7;
    int bi = p + 6 - (i - si);
    int bj = qq + 6 - (j - sj);
    val = sc[head][n] + rpb[(head * 13 + bi) * 13 + bj];
  }
  float m = val;
#pragma unroll
  for (int off = 32; off >= 1; off >>= 1) m = fmaxf(m, __shfl_xor(m, off));
  float e = (n < 49) ? __expf(val - m) : 0.f;
  float s = e;
#pragma unroll
  for (int off = 32; off >= 1; off >>= 1) s += __shfl_xor(s, off);
  __syncthreads();
  if (n < 49) sc[head][n] = e / s;
  __syncthreads();

  float acc = 0.f;
  for (int nn = half; nn < 49; nn += 2) {
    int p = nn / 7, qq = nn % 7;
    int np_ = ((b * 64 + si + p) * 64 + (sj + qq));
    acc += sc[head][nn] * __bfloat162float(qkv[(size_t)np_ * 384 + 256 + head * 32 + dim]);
  }
  acc += __shfl_xor(acc, 32);
  if (half == 0) out[(size_t)pix * 128 + head * 32 + dim] = acc;
}

// ---------- LayerNorm over C + transpose to (B,C,H,W), fp32 store ----------
__global__ __launch_bounds__(256) void ln_out(const float* __restrict__ y,
                                              const float* __restrict__ g,
                                              const float* __restrict__ bta,
                                              float* __restrict__ out) {
  __shared__ float tile[64][129];
  __shared__ float mean_s[64], rstd_s[64];
  int blk = blockIdx.x;            // b*64 + i
  int b = blk >> 6, i = blk & 63;
  int tid = threadIdx.x;
  const float* yrow = y + (size_t)blk * 64 * 128;
  for (int idx = tid; idx < 8192; idx += 256) {
    int j = idx >> 7, c = idx & 127;
    tile[j][c] = yrow[idx];
  }
  __syncthreads();
  int jj = tid >> 2, qtr = tid & 3;
  float sum = 0.f, sumsq = 0.f;
#pragma unroll
  for (int cc = 0; cc < 32; ++cc) {
    float v = tile[jj][qtr * 32 + cc];
    sum += v; sumsq += v * v;
  }
  sum += __shfl_xor(sum, 1);  sum += __shfl_xor(sum, 2);
  sumsq += __shfl_xor(sumsq, 1);  sumsq += __shfl_xor(sumsq, 2);
  if (qtr == 0) {
    float mu = sum * (1.f / 128.f);
    mean_s[jj] = mu;
    rstd_s[jj] = rsqrtf(sumsq * (1.f / 128.f) - mu * mu + 1e-5f);
  }
  __syncthreads();
  int c0 = tid >> 6;       // 0..3
  int j = tid & 63;
  for (int c = c0; c < 128; c += 4) {
    float v = (tile[j][c] - mean_s[j]) * rstd_s[j] * g[c] + bta[c];
    out[(((size_t)b * 128 + c) * 64 + i) * 64 + j] = v;
  }
}

extern "C" void kernel_launch(void* const* d_in, const int* in_sizes, int n_in,
                              void* d_out, int out_size, void* d_ws, size_t ws_size,
                              hipStream_t stream) {
  (void)in_sizes; (void)n_in; (void)out_size; (void)ws_size;
  const float* x   = (const float*)d_in[0];
  const float* qw  = (const float*)d_in[1];   // (2,384,128)
  const float* qb  = (const float*)d_in[2];   // (2,384)
  const float* rpb = (const float*)d_in[3];   // (2,4,13,13)
  const float* pw  = (const float*)d_in[4];   // (2,128,128)
  const float* pb  = (const float*)d_in[5];   // (2,128)
  const float* lg  = (const float*)d_in[6];
  const float* lb  = (const float*)d_in[7];

  float* yb   = (float*)d_ws;                        // PIX*128 fp32 (4 MB)
  bf16*  qkv  = (bf16*)(yb + (size_t)PIX * 128);     // PIX*384 bf16 (6 MB)
  float* attn = (float*)d_out;                        // PIX*128 fp32 scratch (lower 4 MB of 8 MB)
  float* out  = (float*)d_out;

  transpose_in<<<128, 256, 0, stream>>>(x, yb);
  for (int l = 0; l < 2; ++l) {
    gemm_nt<bf16><<<dim3(128, 6), 256, 0, stream>>>(yb, qw + l * 49152, qb + l * 384, qkv, 384);
    na_attn<<<PIX, 256, 0, stream>>>(qkv, rpb + l * 676, attn);
    gemm_nt<float><<<dim3(128, 2), 256, 0, stream>>>(attn, pw + l * 16384, pb + l * 128, yb, 128);
  }
  ln_out<<<128, 256, 0, stream>>>(yb, lg, lb, out);
}

// Round 6
// 236.638 us; speedup vs baseline: 1.4538x; 1.4538x over previous
//
#include <hip/hip_runtime.h>
#include <hip/hip_bf16.h>
#include <math.h>

// B=2, C=128, H=W=64, heads=4, head_dim=32, kernel=7 (49 taps), depth=2.
// Inputs fp32, OUTPUT fp32. qkv intermediate bf16; y/attn fp32.
// ws = y fp32 (4MB) + qkv bf16 (6MB); attn scratch in d_out lower half.
#define PIX 8192            // B*H*W
typedef __hip_bfloat16 bf16;

__device__ inline void store_val(bf16* p, float v)  { *p = __float2bfloat16(v); }
__device__ inline void store_val(float* p, float v) { *p = v; }
__device__ inline float bflo(unsigned u) { return __uint_as_float(u << 16); }
__device__ inline float bfhi(unsigned u) { return __uint_as_float(u & 0xffff0000u); }

// ---------- input transpose: x (B,C,H,W) fp32 -> y (B,H,W,C) fp32 ----------
__global__ __launch_bounds__(256) void transpose_in(const float* __restrict__ x,
                                                    float* __restrict__ y) {
  __shared__ float tile[64][129];
  int blk = blockIdx.x;                      // b*64 + i
  int tid = threadIdx.x;
  int b = blk >> 6, i = blk & 63;
  const float* xbase = x + (size_t)b * 128 * 4096 + (size_t)i * 64;
  for (int idx = tid; idx < 8192; idx += 256) {
    int c = idx >> 6, j = idx & 63;
    tile[j][c] = xbase[(size_t)c * 4096 + j];
  }
  __syncthreads();
  float* yrow = y + (size_t)blk * 64 * 128;
  for (int idx = tid; idx < 8192; idx += 256) {
    int j = idx >> 7, c = idx & 127;
    yrow[idx] = tile[j][c];
  }
}

// ---------- GEMM: C[M,N] = A[M,128] * W[N,128]^T + bias, M=8192 ----------
template <typename OutT>
__global__ __launch_bounds__(256) void gemm_nt(const float* __restrict__ A,
                                               const float* __restrict__ W,
                                               const float* __restrict__ bias,
                                               OutT* __restrict__ Cmat, int N) {
  __shared__ float As[64][65];
  __shared__ float Ws[64][65];
  int m0 = blockIdx.x * 64;
  int n0 = blockIdx.y * 64;
  int tid = threadIdx.x;
  int tx = tid & 15, ty = tid >> 4;
  float acc[4][4] = {{0.f}};
  for (int k0 = 0; k0 < 128; k0 += 64) {
    for (int idx = tid; idx < 4096; idx += 256) {
      int r = idx >> 6, c = idx & 63;
      As[r][c] = A[(size_t)(m0 + r) * 128 + k0 + c];
      Ws[r][c] = W[(size_t)(n0 + r) * 128 + k0 + c];
    }
    __syncthreads();
#pragma unroll 4
    for (int kk = 0; kk < 64; ++kk) {
      float a[4], w[4];
#pragma unroll
      for (int i = 0; i < 4; ++i) a[i] = As[ty * 4 + i][kk];
#pragma unroll
      for (int j = 0; j < 4; ++j) w[j] = Ws[tx * 4 + j][kk];
#pragma unroll
      for (int i = 0; i < 4; ++i)
#pragma unroll
        for (int j = 0; j < 4; ++j) acc[i][j] += a[i] * w[j];
    }
    __syncthreads();
  }
#pragma unroll
  for (int j = 0; j < 4; ++j) {
    float bv = bias[n0 + tx * 4 + j];
#pragma unroll
    for (int i = 0; i < 4; ++i)
      store_val(&Cmat[(size_t)(m0 + ty * 4 + i) * N + n0 + tx * 4 + j],
                acc[i][j] + bv);
  }
}

// ---------- neighborhood attention v2: 8x8 tile x 2 heads per block ----------
// grid (64 tiles, 2 head-pairs, 2 batch), block 128 = 64 pixels x 2 heads.
// K/V halo (14x14) staged in LDS as bf16, row stride 40 ushorts (80 B) =>
// the 8-lane pj pattern (n*20)%32 tiles all 32 banks conflict-free.
#define HSTRIDE 40
__global__ __launch_bounds__(128) void na_attn(const bf16* __restrict__ qkv_,
                                               const float* __restrict__ rpb,
                                               float* __restrict__ out) {
  __shared__ __align__(16) unsigned short kb[2 * 196 * HSTRIDE];
  __shared__ __align__(16) unsigned short vb[2 * 196 * HSTRIDE];
  __shared__ float rb[338];
  const unsigned short* qkvp = (const unsigned short*)qkv_;

  int ti = blockIdx.x >> 3, tj = blockIdx.x & 7;
  int hp = blockIdx.y;           // head pair 0..1
  int bz = blockIdx.z;           // batch
  int tid = threadIdx.x;
  int bi0 = ti * 8 - 3, bj0 = tj * 8 - 3;

  // stage rpb for heads {2hp, 2hp+1}
  for (int t = tid; t < 338; t += 128) rb[t] = rpb[hp * 338 + t];

  // stage K/V halo: 196 rows x (8 K-chunks + 8 V-chunks of 16 B)
  for (int t = tid; t < 3136; t += 128) {
    int row = t >> 4;            // 0..195
    int sub = t & 15;
    int isv = sub >> 3;
    int l8 = sub & 7;
    int ri = row / 14, rj = row - ri * 14;
    int gi = bi0 + ri, gj = bj0 + rj;
    if ((unsigned)gi < 64u && (unsigned)gj < 64u) {
      int pixn = (bz * 64 + gi) * 64 + gj;
      const uint4* src =
          (const uint4*)(qkvp + (size_t)pixn * 384 + 128 + isv * 128 + hp * 64);
      uint4 val = src[l8];
      int hh = l8 >> 2, d0 = (l8 & 3) * 8;
      unsigned short* dst = (isv ? vb : kb) + (hh * 196 + row) * HSTRIDE + d0;
      *(uint4*)dst = val;
    }
  }
  __syncthreads();

  int h = tid >> 6, lane = tid & 63;
  int pi = lane >> 3, pj = lane & 7;
  int i = ti * 8 + pi, j = tj * 8 + pj;
  int si = min(max(i - 3, 0), 57), sj = min(max(j - 3, 0), 57);
  int li = si - bi0, lj = sj - bj0;
  int oi = i - si, oj = j - sj;
  int H = hp * 2 + h;
  int pix = (bz * 64 + i) * 64 + j;

  // q fragment, pre-scaled
  const float scale = 0.17677669529663687f;   // 32^-0.5
  float q[32];
  {
    const uint4* qp4 = (const uint4*)(qkvp + (size_t)pix * 384 + H * 32);
#pragma unroll
    for (int r = 0; r < 4; ++r) {
      uint4 t = qp4[r];
      q[r*8+0] = bflo(t.x) * scale;  q[r*8+1] = bfhi(t.x) * scale;
      q[r*8+2] = bflo(t.y) * scale;  q[r*8+3] = bfhi(t.y) * scale;
      q[r*8+4] = bflo(t.z) * scale;  q[r*8+5] = bfhi(t.z) * scale;
      q[r*8+6] = bflo(t.w) * scale;  q[r*8+7] = bfhi(t.w) * scale;
    }
  }

  // scores
  float s49[49];
  const unsigned short* kh = kb + h * 196 * HSTRIDE;
#pragma unroll
  for (int p = 0; p < 7; ++p) {
#pragma unroll
    for (int qq = 0; qq < 7; ++qq) {
      int n = (li + p) * 14 + (lj + qq);
      const uint4* kp = (const uint4*)(kh + n * HSTRIDE);
      float dot = 0.f;
#pragma unroll
      for (int r = 0; r < 4; ++r) {
        uint4 t = kp[r];
        dot += q[r*8+0] * bflo(t.x);  dot += q[r*8+1] * bfhi(t.x);
        dot += q[r*8+2] * bflo(t.y);  dot += q[r*8+3] * bfhi(t.y);
        dot += q[r*8+4] * bflo(t.z);  dot += q[r*8+5] * bfhi(t.z);
        dot += q[r*8+6] * bflo(t.w);  dot += q[r*8+7] * bfhi(t.w);
      }
      s49[p*7+qq] = dot + rb[h * 169 + (p + 6 - oi) * 13 + (qq + 6 - oj)];
    }
  }

  // softmax
  float m = s49[0];
#pragma unroll
  for (int t = 1; t < 49; ++t) m = fmaxf(m, s49[t]);
  float sum = 0.f;
#pragma unroll
  for (int t = 0; t < 49; ++t) { s49[t] = __expf(s49[t] - m); sum += s49[t]; }
  float inv = 1.f / sum;

  // P @ V
  float acc[32];
#pragma unroll
  for (int d = 0; d < 32; ++d) acc[d] = 0.f;
  const unsigned short* vh = vb + h * 196 * HSTRIDE;
#pragma unroll
  for (int p = 0; p < 7; ++p) {
#pragma unroll
    for (int qq = 0; qq < 7; ++qq) {
      float w = s49[p*7+qq];
      int n = (li + p) * 14 + (lj + qq);
      const uint4* vp = (const uint4*)(vh + n * HSTRIDE);
#pragma unroll
      for (int r = 0; r < 4; ++r) {
        uint4 t = vp[r];
        acc[r*8+0] += w * bflo(t.x);  acc[r*8+1] += w * bfhi(t.x);
        acc[r*8+2] += w * bflo(t.y);  acc[r*8+3] += w * bfhi(t.y);
        acc[r*8+4] += w * bflo(t.z);  acc[r*8+5] += w * bfhi(t.z);
        acc[r*8+6] += w * bflo(t.w);  acc[r*8+7] += w * bfhi(t.w);
      }
    }
  }
  float* op = out + (size_t)pix * 128 + H * 32;
#pragma unroll
  for (int r = 0; r < 8; ++r)
    ((float4*)op)[r] = make_float4(acc[r*4+0]*inv, acc[r*4+1]*inv,
                                   acc[r*4+2]*inv, acc[r*4+3]*inv);
}

// ---------- LayerNorm over C + transpose to (B,C,H,W), fp32 store ----------
__global__ __launch_bounds__(256) void ln_out(const float* __restrict__ y,
                                              const float* __restrict__ g,
                                              const float* __restrict__ bta,
                                              float* __restrict__ out) {
  __shared__ float tile[64][129];
  __shared__ float mean_s[64], rstd_s[64];
  int blk = blockIdx.x;            // b*64 + i
  int b = blk >> 6, i = blk & 63;
  int tid = threadIdx.x;
  const float* yrow = y + (size_t)blk * 64 * 128;
  for (int idx = tid; idx < 8192; idx += 256) {
    int j = idx >> 7, c = idx & 127;
    tile[j][c] = yrow[idx];
  }
  __syncthreads();
  int jj = tid >> 2, qtr = tid & 3;
  float sum = 0.f, sumsq = 0.f;
#pragma unroll
  for (int cc = 0; cc < 32; ++cc) {
    float v = tile[jj][qtr * 32 + cc];
    sum += v; sumsq += v * v;
  }
  sum += __shfl_xor(sum, 1);  sum += __shfl_xor(sum, 2);
  sumsq += __shfl_xor(sumsq, 1);  sumsq += __shfl_xor(sumsq, 2);
  if (qtr == 0) {
    float mu = sum * (1.f / 128.f);
    mean_s[jj] = mu;
    rstd_s[jj] = rsqrtf(sumsq * (1.f / 128.f) - mu * mu + 1e-5f);
  }
  __syncthreads();
  int c0 = tid >> 6;
  int j = tid & 63;
  for (int c = c0; c < 128; c += 4) {
    float v = (tile[j][c] - mean_s[j]) * rstd_s[j] * g[c] + bta[c];
    out[(((size_t)b * 128 + c) * 64 + i) * 64 + j] = v;
  }
}

extern "C" void kernel_launch(void* const* d_in, const int* in_sizes, int n_in,
                              void* d_out, int out_size, void* d_ws, size_t ws_size,
                              hipStream_t stream) {
  (void)in_sizes; (void)n_in; (void)out_size; (void)ws_size;
  const float* x   = (const float*)d_in[0];
  const float* qw  = (const float*)d_in[1];   // (2,384,128)
  const float* qb  = (const float*)d_in[2];   // (2,384)
  const float* rpb = (const float*)d_in[3];   // (2,4,13,13)
  const float* pw  = (const float*)d_in[4];   // (2,128,128)
  const float* pb  = (const float*)d_in[5];   // (2,128)
  const float* lg  = (const float*)d_in[6];
  const float* lb  = (const float*)d_in[7];

  float* yb   = (float*)d_ws;                        // PIX*128 fp32 (4 MB)
  bf16*  qkv  = (bf16*)(yb + (size_t)PIX * 128);     // PIX*384 bf16 (6 MB)
  float* attn = (float*)d_out;                       // scratch (lower 4 MB)
  float* out  = (float*)d_out;

  transpose_in<<<128, 256, 0, stream>>>(x, yb);
  for (int l = 0; l < 2; ++l) {
    gemm_nt<bf16><<<dim3(128, 6), 256, 0, stream>>>(yb, qw + l * 49152, qb + l * 384, qkv, 384);
    na_attn<<<dim3(64, 2, 2), 128, 0, stream>>>(qkv, rpb + l * 676, attn);
    gemm_nt<float><<<dim3(128, 2), 256, 0, stream>>>(attn, pw + l * 16384, pb + l * 128, yb, 128);
  }
  ln_out<<<128, 256, 0, stream>>>(yb, lg, lb, out);
}

// Round 7
// 177.874 us; speedup vs baseline: 1.9341x; 1.3304x over previous
//
#include <hip/hip_runtime.h>
#include <hip/hip_bf16.h>
#include <math.h>

// B=2, C=128, H=W=64, heads=4, head_dim=32, kernel=7 (49 taps), depth=2.
// Inputs fp32, OUTPUT fp32. All intermediates bf16 (fp32 accumulation).
// GEMMs: MFMA 16x16x32 bf16, LDS-free (direct global fragment loads).
// ws: y bf16 (2MB) + qkv bf16 (6MB) + bf16 weights (0.25MB) = 8.25 MB.
// attn intermediate (bf16, 2MB) lives in d_out until the final LN write.
#define PIX 8192            // B*H*W
typedef __hip_bfloat16 bf16;
typedef __attribute__((ext_vector_type(8))) short short8;
typedef __attribute__((ext_vector_type(4))) float f32x4;

__device__ inline float bflo(unsigned u) { return __uint_as_float(u << 16); }
__device__ inline float bfhi(unsigned u) { return __uint_as_float(u & 0xffff0000u); }
__device__ inline unsigned short f2b(float f) {
  __hip_bfloat16 h = __float2bfloat16(f);
  return *reinterpret_cast<unsigned short*>(&h);
}
__device__ inline unsigned pack2(float a, float b) {
  return (unsigned)f2b(a) | ((unsigned)f2b(b) << 16);
}

// ---------- weight conversion: fp32 -> bf16, once per launch ----------
__global__ __launch_bounds__(256) void cvt_w(const float* __restrict__ qw,
                                             const float* __restrict__ pw,
                                             unsigned short* __restrict__ wq,
                                             unsigned short* __restrict__ wp) {
  int idx = blockIdx.x * 256 + threadIdx.x;       // grid 384 -> 98304
  if (idx < 98304) wq[idx] = f2b(qw[idx]);
  if (idx < 32768) wp[idx] = f2b(pw[idx]);
}

// ---------- input transpose: x (B,C,H,W) fp32 -> y (B,H,W,C) bf16 ----------
__global__ __launch_bounds__(256) void transpose_in(const float* __restrict__ x,
                                                    unsigned short* __restrict__ y) {
  __shared__ float tile[64][129];
  int blk = blockIdx.x;                      // b*64 + i
  int tid = threadIdx.x;
  int b = blk >> 6, i = blk & 63;
  const float* xbase = x + (size_t)b * 128 * 4096 + (size_t)i * 64;
  for (int idx = tid; idx < 8192; idx += 256) {
    int c = idx >> 6, j = idx & 63;
    tile[j][c] = xbase[(size_t)c * 4096 + j];
  }
  __syncthreads();
  unsigned short* yrow = y + (size_t)blk * 64 * 128;
  for (int idx = tid; idx < 8192; idx += 256) {
    int j = idx >> 7, c = idx & 127;
    yrow[idx] = f2b(tile[j][c]);
  }
}

// ---------- MFMA GEMM: C[M,N] = A[M,128] * W[N,128]^T + bias ----------
// A, W bf16 row-major (K=128 contiguous). Block 256 = 4 waves; tile 64x64.
// Wave w: rows [m0+16w, +16). Fragments loaded straight from global:
//   A frag: A[m=lane&15][k=quad*8+j]  -> 16B load, no LDS, no barrier.
__global__ __launch_bounds__(256) void gemm_mfma(const unsigned short* __restrict__ A,
                                                 const unsigned short* __restrict__ W,
                                                 const float* __restrict__ bias,
                                                 unsigned short* __restrict__ Cmat,
                                                 int N) {
  int m0 = blockIdx.x * 64, n0 = blockIdx.y * 64;
  int tid = threadIdx.x;
  int w = tid >> 6, lane = tid & 63;
  int quad = lane >> 4, l16 = lane & 15;

  const short8* ap =
      (const short8*)(A + (size_t)(m0 + w * 16 + l16) * 128 + quad * 8);
  short8 a[4];
#pragma unroll
  for (int kc = 0; kc < 4; ++kc) a[kc] = ap[kc * 4];

  f32x4 acc[4];
#pragma unroll
  for (int nt = 0; nt < 4; ++nt) {
    const short8* bp =
        (const short8*)(W + (size_t)(n0 + nt * 16 + l16) * 128 + quad * 8);
    f32x4 c = {0.f, 0.f, 0.f, 0.f};
#pragma unroll
    for (int kc = 0; kc < 4; ++kc)
      c = __builtin_amdgcn_mfma_f32_16x16x32_bf16(a[kc], bp[kc * 4], c, 0, 0, 0);
    acc[nt] = c;
  }

#pragma unroll
  for (int nt = 0; nt < 4; ++nt) {
    int col = n0 + nt * 16 + l16;               // C/D: col = lane&15
    float bv = bias[col];
#pragma unroll
    for (int r = 0; r < 4; ++r) {               // row = quad*4 + reg
      int m = m0 + w * 16 + quad * 4 + r;
      Cmat[(size_t)m * N + col] = f2b(acc[nt][r] + bv);
    }
  }
}

// ---------- neighborhood attention: 8x8 tile x 2 heads per block ----------
#define HSTRIDE 40
__global__ __launch_bounds__(128) void na_attn(const unsigned short* __restrict__ qkvp,
                                               const float* __restrict__ rpb,
                                               unsigned short* __restrict__ out) {
  __shared__ __align__(16) unsigned short kb[2 * 196 * HSTRIDE];
  __shared__ __align__(16) unsigned short vb[2 * 196 * HSTRIDE];
  __shared__ float rb[338];

  int ti = blockIdx.x >> 3, tj = blockIdx.x & 7;
  int hp = blockIdx.y;           // head pair 0..1
  int bz = blockIdx.z;           // batch
  int tid = threadIdx.x;
  int bi0 = ti * 8 - 3, bj0 = tj * 8 - 3;

  for (int t = tid; t < 338; t += 128) rb[t] = rpb[hp * 338 + t];

  for (int t = tid; t < 3136; t += 128) {
    int row = t >> 4;            // 0..195
    int sub = t & 15;
    int isv = sub >> 3;
    int l8 = sub & 7;
    int ri = row / 14, rj = row - ri * 14;
    int gi = bi0 + ri, gj = bj0 + rj;
    if ((unsigned)gi < 64u && (unsigned)gj < 64u) {
      int pixn = (bz * 64 + gi) * 64 + gj;
      const uint4* src =
          (const uint4*)(qkvp + (size_t)pixn * 384 + 128 + isv * 128 + hp * 64);
      uint4 val = src[l8];
      int hh = l8 >> 2, d0 = (l8 & 3) * 8;
      unsigned short* dst = (isv ? vb : kb) + (hh * 196 + row) * HSTRIDE + d0;
      *(uint4*)dst = val;
    }
  }
  __syncthreads();

  int h = tid >> 6, lane = tid & 63;
  int pi = lane >> 3, pj = lane & 7;
  int i = ti * 8 + pi, j = tj * 8 + pj;
  int si = min(max(i - 3, 0), 57), sj = min(max(j - 3, 0), 57);
  int li = si - bi0, lj = sj - bj0;
  int oi = i - si, oj = j - sj;
  int H = hp * 2 + h;
  int pix = (bz * 64 + i) * 64 + j;

  const float scale = 0.17677669529663687f;   // 32^-0.5
  float q[32];
  {
    const uint4* qp4 = (const uint4*)(qkvp + (size_t)pix * 384 + H * 32);
#pragma unroll
    for (int r = 0; r < 4; ++r) {
      uint4 t = qp4[r];
      q[r*8+0] = bflo(t.x) * scale;  q[r*8+1] = bfhi(t.x) * scale;
      q[r*8+2] = bflo(t.y) * scale;  q[r*8+3] = bfhi(t.y) * scale;
      q[r*8+4] = bflo(t.z) * scale;  q[r*8+5] = bfhi(t.z) * scale;
      q[r*8+6] = bflo(t.w) * scale;  q[r*8+7] = bfhi(t.w) * scale;
    }
  }

  float s49[49];
  const unsigned short* kh = kb + h * 196 * HSTRIDE;
#pragma unroll
  for (int p = 0; p < 7; ++p) {
#pragma unroll
    for (int qq = 0; qq < 7; ++qq) {
      int n = (li + p) * 14 + (lj + qq);
      const uint4* kp = (const uint4*)(kh + n * HSTRIDE);
      float dot = 0.f;
#pragma unroll
      for (int r = 0; r < 4; ++r) {
        uint4 t = kp[r];
        dot += q[r*8+0] * bflo(t.x);  dot += q[r*8+1] * bfhi(t.x);
        dot += q[r*8+2] * bflo(t.y);  dot += q[r*8+3] * bfhi(t.y);
        dot += q[r*8+4] * bflo(t.z);  dot += q[r*8+5] * bfhi(t.z);
        dot += q[r*8+6] * bflo(t.w);  dot += q[r*8+7] * bfhi(t.w);
      }
      s49[p*7+qq] = dot + rb[h * 169 + (p + 6 - oi) * 13 + (qq + 6 - oj)];
    }
  }

  float m = s49[0];
#pragma unroll
  for (int t = 1; t < 49; ++t) m = fmaxf(m, s49[t]);
  float sum = 0.f;
#pragma unroll
  for (int t = 0; t < 49; ++t) { s49[t] = __expf(s49[t] - m); sum += s49[t]; }
  float inv = 1.f / sum;

  float acc[32];
#pragma unroll
  for (int d = 0; d < 32; ++d) acc[d] = 0.f;
  const unsigned short* vh = vb + h * 196 * HSTRIDE;
#pragma unroll
  for (int p = 0; p < 7; ++p) {
#pragma unroll
    for (int qq = 0; qq < 7; ++qq) {
      float w = s49[p*7+qq];
      int n = (li + p) * 14 + (lj + qq);
      const uint4* vp = (const uint4*)(vh + n * HSTRIDE);
#pragma unroll
      for (int r = 0; r < 4; ++r) {
        uint4 t = vp[r];
        acc[r*8+0] += w * bflo(t.x);  acc[r*8+1] += w * bfhi(t.x);
        acc[r*8+2] += w * bflo(t.y);  acc[r*8+3] += w * bfhi(t.y);
        acc[r*8+4] += w * bflo(t.z);  acc[r*8+5] += w * bfhi(t.z);
        acc[r*8+6] += w * bflo(t.w);  acc[r*8+7] += w * bfhi(t.w);
      }
    }
  }
  unsigned short* op = out + (size_t)pix * 128 + H * 32;
#pragma unroll
  for (int r = 0; r < 4; ++r) {
    uint4 t;
    t.x = pack2(acc[r*8+0]*inv, acc[r*8+1]*inv);
    t.y = pack2(acc[r*8+2]*inv, acc[r*8+3]*inv);
    t.z = pack2(acc[r*8+4]*inv, acc[r*8+5]*inv);
    t.w = pack2(acc[r*8+6]*inv, acc[r*8+7]*inv);
    ((uint4*)op)[r] = t;
  }
}

// ---------- LayerNorm over C + transpose to (B,C,H,W), fp32 store ----------
__global__ __launch_bounds__(256) void ln_out(const unsigned short* __restrict__ y,
                                              const float* __restrict__ g,
                                              const float* __restrict__ bta,
                                              float* __restrict__ out) {
  __shared__ float tile[64][129];
  __shared__ float mean_s[64], rstd_s[64];
  int blk = blockIdx.x;            // b*64 + i
  int b = blk >> 6, i = blk & 63;
  int tid = threadIdx.x;
  const unsigned short* yrow = y + (size_t)blk * 64 * 128;
  for (int idx = tid; idx < 8192; idx += 256) {
    int j = idx >> 7, c = idx & 127;
    tile[j][c] = __uint_as_float((unsigned)yrow[idx] << 16);
  }
  __syncthreads();
  int jj = tid >> 2, qtr = tid & 3;
  float sum = 0.f, sumsq = 0.f;
#pragma unroll
  for (int cc = 0; cc < 32; ++cc) {
    float v = tile[jj][qtr * 32 + cc];
    sum += v; sumsq += v * v;
  }
  sum += __shfl_xor(sum, 1);  sum += __shfl_xor(sum, 2);
  sumsq += __shfl_xor(sumsq, 1);  sumsq += __shfl_xor(sumsq, 2);
  if (qtr == 0) {
    float mu = sum * (1.f / 128.f);
    mean_s[jj] = mu;
    rstd_s[jj] = rsqrtf(sumsq * (1.f / 128.f) - mu * mu + 1e-5f);
  }
  __syncthreads();
  int c0 = tid >> 6;
  int j = tid & 63;
  for (int c = c0; c < 128; c += 4) {
    float v = (tile[j][c] - mean_s[j]) * rstd_s[j] * g[c] + bta[c];
    out[(((size_t)b * 128 + c) * 64 + i) * 64 + j] = v;
  }
}

extern "C" void kernel_launch(void* const* d_in, const int* in_sizes, int n_in,
                              void* d_out, int out_size, void* d_ws, size_t ws_size,
                              hipStream_t stream) {
  (void)in_sizes; (void)n_in; (void)out_size; (void)ws_size;
  const float* x   = (const float*)d_in[0];
  const float* qw  = (const float*)d_in[1];   // (2,384,128)
  const float* qb  = (const float*)d_in[2];   // (2,384)
  const float* rpb = (const float*)d_in[3];   // (2,4,13,13)
  const float* pw  = (const float*)d_in[4];   // (2,128,128)
  const float* pb  = (const float*)d_in[5];   // (2,128)
  const float* lg  = (const float*)d_in[6];
  const float* lb  = (const float*)d_in[7];

  unsigned short* y    = (unsigned short*)d_ws;          // PIX*128 (2 MB)
  unsigned short* qkv  = y + (size_t)PIX * 128;          // PIX*384 (6 MB)
  unsigned short* wq   = qkv + (size_t)PIX * 384;        // 98304   (192 KB)
  unsigned short* wp   = wq + 98304;                     // 32768   (64 KB)
  unsigned short* attn = (unsigned short*)d_out;         // PIX*128 (2 MB scratch)
  float* out = (float*)d_out;

  cvt_w<<<384, 256, 0, stream>>>(qw, pw, wq, wp);
  transpose_in<<<128, 256, 0, stream>>>(x, y);
  for (int l = 0; l < 2; ++l) {
    gemm_mfma<<<dim3(128, 6), 256, 0, stream>>>(y, wq + l * 49152, qb + l * 384, qkv, 384);
    na_attn<<<dim3(64, 2, 2), 128, 0, stream>>>(qkv, rpb + l * 676, attn);
    gemm_mfma<<<dim3(128, 2), 256, 0, stream>>>(attn, wp + l * 16384, pb + l * 128, y, 128);
  }
  ln_out<<<128, 256, 0, stream>>>(y, lg, lb, out);
}